// Round 5
// baseline (279.889 us; speedup 1.0000x reference)
//
#include <hip/hip_runtime.h>

// AirFitMultiHeadDNN — R14: R13 (DS-only operand path + full item per thread)
// with the f-load geometry bug fixed. R13 loaded 30 floats/item ("half-item"
// leftover) so heads 10-19 indexed past fh[] -> NaN. An f row is 60 floats:
// load 30x float2, head h uses floats 3h..3h+2 (max pair index 29).
// Evidence R12: VALU cut 39->30% but dur only 85->76us; no pipe >30% =>
// latency-bound. Mechanism: per-head s_load of M/W2/b2/Wo (global,
// 300-900cy) mixed with ds_read T in lgkmcnt forces full drains per head;
// VGPR=12 => zero cross-head ILP.
// R14: (1) M/W2/b2/Wo staged into LDS (8KB) -> compute phase DS-only,
// fine-grained lgkmcnt(N), uniform-addr broadcast reads (conflict-free).
// (2) Full 20-head item per thread: no atomics, no out-init, 1024 blocks.
// (3) f/e loaded directly per thread (aligned float2/int4; 240B+80B
// contiguous per thread -> lines fully used, wave footprint 15KB fits L1).
// T fp16 stride-6 (6*idx mod 32 distinct -> conflict-free).
// Predicted: dur 76 -> ~50us; conflicts 1.97M -> <100K; FETCH ~90MB
// (>=200MB falsifies direct-load bet); VGPR ~60, no scratch.

#define HH   20
#define NEX  13
#define NT   512

// ws dword-slot layout
#define WS_T   0                 // T16[h][idx][p] : 20*13*6 = 1560 (p=5 pad)
#define WS_M   1560              // M16[h][s]      : 20*16   = 320  (s=15 pad)
#define WS_WB  1880              // WB[h][s]       : 20*8    = 160
#define WS_END 2040              // 8,160 B

typedef _Float16 hv2 __attribute__((ext_vector_type(2)));

__device__ __forceinline__ float softplus_fast(float x) {
    return fmaxf(x, 0.0f) + __logf(1.0f + __expf(-fabsf(x)));
}

__device__ __forceinline__ float fdot2f(hv2 a, hv2 b, float c) {
#if __has_builtin(__builtin_amdgcn_fdot2)
    return __builtin_amdgcn_fdot2(a, b, c, false);
#else
    return fmaf((float)a.x, (float)b.x, fmaf((float)a.y, (float)b.y, c));
#endif
}

// -------- setup: fold weights into fp16 T16/M16 + WB rows --------
__global__ void airfit_setup(const float* __restrict__ emb,
                             const float* __restrict__ Wf,
                             const float* __restrict__ bf,
                             const float* __restrict__ W1,
                             const float* __restrict__ b1,
                             const float* __restrict__ W2,
                             const float* __restrict__ b2,
                             const float* __restrict__ Wo,
                             float* __restrict__ ws)
{
    int t = blockIdx.x * 256 + threadIdx.x;
    hv2* wsh = reinterpret_cast<hv2*>(ws);

    if (t < HH * NEX * 6) {                      // T16[h][idx][p], p=5 pad
        int h = t / (NEX * 6), r = t % (NEX * 6), idx = r / 6, p = r % 6;
        float v[2] = { 0.0f, 0.0f };
        if (p < 5) {
            for (int s = 0; s < 2; ++s) {
                int o = 2 * p + s;
                float a = b1[h * 10 + o];
                for (int i = 0; i < 3; ++i)
                    a += emb[idx * 3 + i] * W1[(h * 8 + i) * 10 + o];
                for (int q = 0; q < 5; ++q)
                    a += bf[q] * W1[(h * 8 + 3 + q) * 10 + o];
                v[s] = a;
            }
        }
        wsh[WS_T + t] = hv2{ (_Float16)v[0], (_Float16)v[1] };
    }
    if (t < HH * 16) {                           // M16[h][c*5+pp], s=15 pad
        int h = t / 16, s = t % 16;
        float v[2] = { 0.0f, 0.0f };
        if (s < 15) {
            int c = s / 5, pp = s % 5;
            for (int sd = 0; sd < 2; ++sd) {
                int o = 2 * pp + sd;
                float a = 0.0f;
                for (int q = 0; q < 5; ++q)
                    a += Wf[c * 5 + q] * W1[(h * 8 + 3 + q) * 10 + o];
                v[sd] = a;
            }
        }
        wsh[WS_M + t] = hv2{ (_Float16)v[0], (_Float16)v[1] };
    }
    if (t < HH * 8) {                            // WB[h]: W2h*5, b2, Wo, pad
        int h = t / 8, s = t % 8;
        float outv = 0.0f;
        if (s < 5)
            outv = __builtin_bit_cast(float,
                       hv2{ (_Float16)W2[h * 10 + 2 * s],
                            (_Float16)W2[h * 10 + 2 * s + 1] });
        else if (s == 5) outv = b2[h];
        else if (s == 6) outv = Wo[h];
        ws[WS_WB + t] = outv;
    }
}

// -------- main: full item (20 heads) per thread --------
__global__ __launch_bounds__(NT, 8) void airfit_kernel(
    const int*   __restrict__ e,   const float* __restrict__ f,
    const float* __restrict__ ws,  const float* __restrict__ bo,
    float* __restrict__ out, int B)
{
    __shared__ __align__(16) float s_c[WS_END];  // 8,160 B

    const int tid  = threadIdx.x;
    const int base = blockIdx.x * NT;
    const int nIt  = min(NT, B - base);

    for (int t = tid; t < WS_END; t += NT) s_c[t] = ws[t];
    __syncthreads();                             // only barrier

    if (tid >= nIt) return;
    const int item = base + tid;

    // ---- e: 5x int4 (16B-aligned: item*80B) -> 20 nibbles in 3 dwords ----
    const int4* eg = reinterpret_cast<const int4*>(e + (size_t)item * HH);
    int4 e0 = eg[0], e1 = eg[1], e2 = eg[2], e3 = eg[3], e4 = eg[4];
    unsigned ew0 = (unsigned)(e0.x & 15)        | ((unsigned)(e0.y & 15) << 4)
                 | ((unsigned)(e0.z & 15) << 8) | ((unsigned)(e0.w & 15) << 12)
                 | ((unsigned)(e1.x & 15) << 16)| ((unsigned)(e1.y & 15) << 20)
                 | ((unsigned)(e1.z & 15) << 24)| ((unsigned)(e1.w & 15) << 28);
    unsigned ew1 = (unsigned)(e2.x & 15)        | ((unsigned)(e2.y & 15) << 4)
                 | ((unsigned)(e2.z & 15) << 8) | ((unsigned)(e2.w & 15) << 12)
                 | ((unsigned)(e3.x & 15) << 16)| ((unsigned)(e3.y & 15) << 20)
                 | ((unsigned)(e3.z & 15) << 24)| ((unsigned)(e3.w & 15) << 28);
    unsigned ew2 = (unsigned)(e4.x & 15)        | ((unsigned)(e4.y & 15) << 4)
                 | ((unsigned)(e4.z & 15) << 8) | ((unsigned)(e4.w & 15) << 12);

    // ---- f: 30x float2 (8B-aligned: item*240B) -> 30 fp16 pairs ----
    const float2* fg = reinterpret_cast<const float2*>(f) + (size_t)item * 30;
    hv2 fh[30];
#pragma unroll
    for (int k = 0; k < 30; ++k) {
        float2 v = fg[k];
        fh[k] = hv2{ (_Float16)v.x, (_Float16)v.y };
    }

    const hv2* Tt = reinterpret_cast<const hv2*>(s_c + WS_T);
    const hv2* Mt = reinterpret_cast<const hv2*>(s_c + WS_M);
    const hv2 lk2 = hv2{ (_Float16)0.01f, (_Float16)0.01f };

    float acc = bo[0];
#pragma unroll
    for (int h = 0; h < HH; ++h) {               // h compile-time
        unsigned word = (h < 8) ? ew0 : ((h < 16) ? ew1 : ew2);
        int idx = (int)((word >> (4 * (h & 7))) & 0xfu);

        const hv2* Tr = Tt + (h * NEX + idx) * 6;
        hv2 tp[5] = { Tr[0], Tr[1], Tr[2], Tr[3], Tr[4] };

        // f floats 3h..3h+2 out of fh[30] (pair index (3h)>>1, max 29)
        const int kb = (3 * h) >> 1;
        _Float16 x0, x1, x2;
        if ((h & 1) == 0) { x0 = fh[kb].x;  x1 = fh[kb].y;  x2 = fh[kb+1].x; }
        else              { x0 = fh[kb].y;  x1 = fh[kb+1].x; x2 = fh[kb+1].y; }
        hv2 g0 = hv2{ x0, x0 }, g1 = hv2{ x1, x1 }, g2 = hv2{ x2, x2 };

        const hv2*   Mh  = Mt + h * 16;          // uniform addr -> broadcast
        const float* wb  = s_c + WS_WB + h * 8;
        const hv2*   W2h = reinterpret_cast<const hv2*>(wb);

        float hacc = wb[5];                      // b2[h]
#pragma unroll
        for (int p = 0; p < 5; ++p) {
            hv2 v = g0 * Mh[p] + tp[p];          // v_pk_fma_f16
            v = g1 * Mh[5 + p] + v;
            v = g2 * Mh[10 + p] + v;
            v = __builtin_elementwise_max(v, v * lk2);  // leaky
            hacc = fdot2f(v, W2h[p], hacc);      // f32 accumulate
        }
        acc = fmaf(softplus_fast(hacc), wb[6], acc);    // Wo[h]
    }

    out[item] = acc;                             // coalesced, no atomics
}

extern "C" void kernel_launch(void* const* d_in, const int* in_sizes, int n_in,
                              void* d_out, int out_size, void* d_ws, size_t ws_size,
                              hipStream_t stream) {
    const int*   e   = (const int*)  d_in[0];
    const float* f   = (const float*)d_in[1];
    const float* emb = (const float*)d_in[2];
    const float* Wf  = (const float*)d_in[3];
    const float* bf  = (const float*)d_in[4];
    const float* W1  = (const float*)d_in[5];
    const float* b1  = (const float*)d_in[6];
    const float* W2  = (const float*)d_in[7];
    const float* b2  = (const float*)d_in[8];
    const float* Wo  = (const float*)d_in[9];
    const float* bo  = (const float*)d_in[10];
    float* out = (float*)d_out;
    float* ws  = (float*)d_ws;

    int B = in_sizes[0] / HH;                    // e is (B, 20)

    int sblocks = (HH * NEX * 6 + 255) / 256;    // 7 blocks covers all tables
    airfit_setup<<<sblocks, 256, 0, stream>>>(emb, Wf, bf, W1, b1, W2, b2, Wo, ws);

    int blocks = (B + NT - 1) / NT;
    airfit_kernel<<<blocks, NT, 0, stream>>>(e, f, ws, bo, out, B);
}

// Round 7
// 267.415 us; speedup vs baseline: 1.0466x; 1.0466x over previous
//
#include <hip/hip_runtime.h>

// AirFitMultiHeadDNN — R16: R15 with cvt_pkrtz return type bit_cast fixed
// (__builtin_amdgcn_cvt_pkrtz returns __fp16x2, not _Float16x2).
// Evidence R14: WRITE_SIZE 4MB->114MB, FETCH 82->234MB, VGPR=32, VALU 13%
// => fh[30] (plus raw float2 load batch) blew the 64-VGPR cap of
// launch_bounds(512,8) and spilled; kernel became a 3TB/s scratch stream.
// Confirmed from R14: bank conflicts = 0 (T stride-6 + uniform broadcasts),
// direct per-thread loads sustain 3TB/s.
// R16: f loaded in two 15-pair chunks, each converted immediately via
// v_cvt_pkrtz_f16_f32 (1 instr/pair). Peak live ~53 VGPR, steady ~50.
// e packed first (transients retire before f chunks). Heads 0-9 use
// chunk0, 10-19 chunk1.
// Predicted: WRITE 114MB -> ~2MB (tripwire; else go launch_bounds(512,6));
// dur 116 -> ~45-60us; VALU ~30-40%; VGPR 56-64 no scratch; conflicts 0.

#define HH   20
#define NEX  13
#define NT   512

// ws dword-slot layout
#define WS_T   0                 // T16[h][idx][p] : 20*13*6 = 1560 (p=5 pad)
#define WS_M   1560              // M16[h][s]      : 20*16   = 320  (s=15 pad)
#define WS_WB  1880              // WB[h][s]       : 20*8    = 160
#define WS_END 2040              // 8,160 B

typedef _Float16 hv2 __attribute__((ext_vector_type(2)));

__device__ __forceinline__ float softplus_fast(float x) {
    return fmaxf(x, 0.0f) + __logf(1.0f + __expf(-fabsf(x)));
}

__device__ __forceinline__ float fdot2f(hv2 a, hv2 b, float c) {
#if __has_builtin(__builtin_amdgcn_fdot2)
    return __builtin_amdgcn_fdot2(a, b, c, false);
#else
    return fmaf((float)a.x, (float)b.x, fmaf((float)a.y, (float)b.y, c));
#endif
}

__device__ __forceinline__ hv2 cvt_pk(float x, float y) {
#if __has_builtin(__builtin_amdgcn_cvt_pkrtz)
    return __builtin_bit_cast(hv2, __builtin_amdgcn_cvt_pkrtz(x, y));
#else
    return hv2{ (_Float16)x, (_Float16)y };
#endif
}

// -------- setup: fold weights into fp16 T16/M16 + WB rows --------
__global__ void airfit_setup(const float* __restrict__ emb,
                             const float* __restrict__ Wf,
                             const float* __restrict__ bf,
                             const float* __restrict__ W1,
                             const float* __restrict__ b1,
                             const float* __restrict__ W2,
                             const float* __restrict__ b2,
                             const float* __restrict__ Wo,
                             float* __restrict__ ws)
{
    int t = blockIdx.x * 256 + threadIdx.x;
    hv2* wsh = reinterpret_cast<hv2*>(ws);

    if (t < HH * NEX * 6) {                      // T16[h][idx][p], p=5 pad
        int h = t / (NEX * 6), r = t % (NEX * 6), idx = r / 6, p = r % 6;
        float v[2] = { 0.0f, 0.0f };
        if (p < 5) {
            for (int s = 0; s < 2; ++s) {
                int o = 2 * p + s;
                float a = b1[h * 10 + o];
                for (int i = 0; i < 3; ++i)
                    a += emb[idx * 3 + i] * W1[(h * 8 + i) * 10 + o];
                for (int q = 0; q < 5; ++q)
                    a += bf[q] * W1[(h * 8 + 3 + q) * 10 + o];
                v[s] = a;
            }
        }
        wsh[WS_T + t] = hv2{ (_Float16)v[0], (_Float16)v[1] };
    }
    if (t < HH * 16) {                           // M16[h][c*5+pp], s=15 pad
        int h = t / 16, s = t % 16;
        float v[2] = { 0.0f, 0.0f };
        if (s < 15) {
            int c = s / 5, pp = s % 5;
            for (int sd = 0; sd < 2; ++sd) {
                int o = 2 * pp + sd;
                float a = 0.0f;
                for (int q = 0; q < 5; ++q)
                    a += Wf[c * 5 + q] * W1[(h * 8 + 3 + q) * 10 + o];
                v[sd] = a;
            }
        }
        wsh[WS_M + t] = hv2{ (_Float16)v[0], (_Float16)v[1] };
    }
    if (t < HH * 8) {                            // WB[h]: W2h*5, b2, Wo, pad
        int h = t / 8, s = t % 8;
        float outv = 0.0f;
        if (s < 5)
            outv = __builtin_bit_cast(float,
                       hv2{ (_Float16)W2[h * 10 + 2 * s],
                            (_Float16)W2[h * 10 + 2 * s + 1] });
        else if (s == 5) outv = b2[h];
        else if (s == 6) outv = Wo[h];
        ws[WS_WB + t] = outv;
    }
}

// -------- main: full item (20 heads) per thread, two f chunks --------
__global__ __launch_bounds__(NT, 8) void airfit_kernel(
    const int*   __restrict__ e,   const float* __restrict__ f,
    const float* __restrict__ ws,  const float* __restrict__ bo,
    float* __restrict__ out, int B)
{
    __shared__ __align__(16) float s_c[WS_END];  // 8,160 B

    const int tid  = threadIdx.x;
    const int base = blockIdx.x * NT;
    const int nIt  = min(NT, B - base);

    for (int t = tid; t < WS_END; t += NT) s_c[t] = ws[t];
    __syncthreads();                             // only barrier

    if (tid >= nIt) return;
    const int item = base + tid;

    // ---- e: 5x int4 (16B-aligned: item*80B) -> 20 nibbles in 3 dwords ----
    // Done FIRST so its 20 transient VGPRs retire before the f chunks.
    const int4* eg = reinterpret_cast<const int4*>(e + (size_t)item * HH);
    int4 e0 = eg[0], e1 = eg[1], e2 = eg[2], e3 = eg[3], e4 = eg[4];
    unsigned ew0 = (unsigned)(e0.x & 15)        | ((unsigned)(e0.y & 15) << 4)
                 | ((unsigned)(e0.z & 15) << 8) | ((unsigned)(e0.w & 15) << 12)
                 | ((unsigned)(e1.x & 15) << 16)| ((unsigned)(e1.y & 15) << 20)
                 | ((unsigned)(e1.z & 15) << 24)| ((unsigned)(e1.w & 15) << 28);
    unsigned ew1 = (unsigned)(e2.x & 15)        | ((unsigned)(e2.y & 15) << 4)
                 | ((unsigned)(e2.z & 15) << 8) | ((unsigned)(e2.w & 15) << 12)
                 | ((unsigned)(e3.x & 15) << 16)| ((unsigned)(e3.y & 15) << 20)
                 | ((unsigned)(e3.z & 15) << 24)| ((unsigned)(e3.w & 15) << 28);
    unsigned ew2 = (unsigned)(e4.x & 15)        | ((unsigned)(e4.y & 15) << 4)
                 | ((unsigned)(e4.z & 15) << 8) | ((unsigned)(e4.w & 15) << 12);

    // ---- f: 60 floats/item in two chunks of 15 float2, cvt_pkrtz each ----
    const float2* fg = reinterpret_cast<const float2*>(f) + (size_t)item * 30;
    hv2 fh0[15], fh1[15];
#pragma unroll
    for (int k = 0; k < 15; ++k) {               // chunk 0: floats 0..29
        float2 v = fg[k];
        fh0[k] = cvt_pk(v.x, v.y);
    }
#pragma unroll
    for (int k = 0; k < 15; ++k) {               // chunk 1: floats 30..59
        float2 v = fg[15 + k];
        fh1[k] = cvt_pk(v.x, v.y);
    }

    const hv2* Tt = reinterpret_cast<const hv2*>(s_c + WS_T);
    const hv2* Mt = reinterpret_cast<const hv2*>(s_c + WS_M);
    const hv2 lk2 = hv2{ (_Float16)0.01f, (_Float16)0.01f };

    float acc = bo[0];
#pragma unroll
    for (int h = 0; h < HH; ++h) {               // h compile-time
        unsigned word = (h < 8) ? ew0 : ((h < 16) ? ew1 : ew2);
        int idx = (int)((word >> (4 * (h & 7))) & 0xfu);

        const hv2* Tr = Tt + (h * NEX + idx) * 6;
        hv2 tp[5] = { Tr[0], Tr[1], Tr[2], Tr[3], Tr[4] };

        // f floats 3h..3h+2; chunk-local pair index (max 14 per chunk)
        const hv2* fc = (h < 10) ? fh0 : fh1;
        const int  hl = (h < 10) ? h : (h - 10);
        const int  kb = (3 * hl) >> 1;
        _Float16 x0, x1, x2;
        if ((hl & 1) == 0) { x0 = fc[kb].x;  x1 = fc[kb].y;   x2 = fc[kb+1].x; }
        else               { x0 = fc[kb].y;  x1 = fc[kb+1].x; x2 = fc[kb+1].y; }
        hv2 g0 = hv2{ x0, x0 }, g1 = hv2{ x1, x1 }, g2 = hv2{ x2, x2 };

        const hv2*   Mh  = Mt + h * 16;          // uniform addr -> broadcast
        const float* wb  = s_c + WS_WB + h * 8;
        const hv2*   W2h = reinterpret_cast<const hv2*>(wb);

        float hacc = wb[5];                      // b2[h]
#pragma unroll
        for (int p = 0; p < 5; ++p) {
            hv2 v = g0 * Mh[p] + tp[p];          // v_pk_fma_f16
            v = g1 * Mh[5 + p] + v;
            v = g2 * Mh[10 + p] + v;
            v = __builtin_elementwise_max(v, v * lk2);  // leaky
            hacc = fdot2f(v, W2h[p], hacc);      // f32 accumulate
        }
        acc = fmaf(softplus_fast(hacc), wb[6], acc);    // Wo[h]
    }

    out[item] = acc;                             // coalesced, no atomics
}

extern "C" void kernel_launch(void* const* d_in, const int* in_sizes, int n_in,
                              void* d_out, int out_size, void* d_ws, size_t ws_size,
                              hipStream_t stream) {
    const int*   e   = (const int*)  d_in[0];
    const float* f   = (const float*)d_in[1];
    const float* emb = (const float*)d_in[2];
    const float* Wf  = (const float*)d_in[3];
    const float* bf  = (const float*)d_in[4];
    const float* W1  = (const float*)d_in[5];
    const float* b1  = (const float*)d_in[6];
    const float* W2  = (const float*)d_in[7];
    const float* b2  = (const float*)d_in[8];
    const float* Wo  = (const float*)d_in[9];
    const float* bo  = (const float*)d_in[10];
    float* out = (float*)d_out;
    float* ws  = (float*)d_ws;

    int B = in_sizes[0] / HH;                    // e is (B, 20)

    int sblocks = (HH * NEX * 6 + 255) / 256;    // 7 blocks covers all tables
    airfit_setup<<<sblocks, 256, 0, stream>>>(emb, Wf, bf, W1, b1, W2, b2, Wo, ws);

    int blocks = (B + NT - 1) / NT;
    airfit_kernel<<<blocks, NT, 0, stream>>>(e, f, ws, bo, out, B);
}

// Round 8
// 246.302 us; speedup vs baseline: 1.1364x; 1.0857x over previous
//
#include <hip/hip_runtime.h>

// AirFitMultiHeadDNN — R17: R16 with register headroom for the load batch.
// Evidence R16: WRITE 114->71.7MB, VGPR stuck at 32 => allocator still
// spills fh[] under launch_bounds(512,8)'s 64-VGPR cap (it batches all 30
// f loads -> 60 raw regs live). FETCH 175MB ~= 168MB compulsory: direct
// per-thread loads waste nothing. Floor: HBM 27us, VALU ~5us, DS ~6us.
// R17: launch_bounds(512,6) -> ~84 VGPR budget, 3 blocks/CU = 24 waves.
// f via 15x float4 (16B-aligned, 240B rows) with immediate cvt_pkrtz.
// Tripwire: WRITE must collapse to ~2MB and VGPR rise to 64-84; else the
// spill theory is dead -> fall back to LDS-staged f at 16 waves.
// Predicted: dur 102.5 -> ~55-70us; VALU ~25-30%; conflicts 0.

#define HH   20
#define NEX  13
#define NT   512

// ws dword-slot layout
#define WS_T   0                 // T16[h][idx][p] : 20*13*6 = 1560 (p=5 pad)
#define WS_M   1560              // M16[h][s]      : 20*16   = 320  (s=15 pad)
#define WS_WB  1880              // WB[h][s]       : 20*8    = 160
#define WS_END 2040              // 8,160 B

typedef _Float16 hv2 __attribute__((ext_vector_type(2)));

__device__ __forceinline__ float softplus_fast(float x) {
    return fmaxf(x, 0.0f) + __logf(1.0f + __expf(-fabsf(x)));
}

__device__ __forceinline__ float fdot2f(hv2 a, hv2 b, float c) {
#if __has_builtin(__builtin_amdgcn_fdot2)
    return __builtin_amdgcn_fdot2(a, b, c, false);
#else
    return fmaf((float)a.x, (float)b.x, fmaf((float)a.y, (float)b.y, c));
#endif
}

__device__ __forceinline__ hv2 cvt_pk(float x, float y) {
#if __has_builtin(__builtin_amdgcn_cvt_pkrtz)
    return __builtin_bit_cast(hv2, __builtin_amdgcn_cvt_pkrtz(x, y));
#else
    return hv2{ (_Float16)x, (_Float16)y };
#endif
}

// -------- setup: fold weights into fp16 T16/M16 + WB rows --------
__global__ void airfit_setup(const float* __restrict__ emb,
                             const float* __restrict__ Wf,
                             const float* __restrict__ bf,
                             const float* __restrict__ W1,
                             const float* __restrict__ b1,
                             const float* __restrict__ W2,
                             const float* __restrict__ b2,
                             const float* __restrict__ Wo,
                             float* __restrict__ ws)
{
    int t = blockIdx.x * 256 + threadIdx.x;
    hv2* wsh = reinterpret_cast<hv2*>(ws);

    if (t < HH * NEX * 6) {                      // T16[h][idx][p], p=5 pad
        int h = t / (NEX * 6), r = t % (NEX * 6), idx = r / 6, p = r % 6;
        float v[2] = { 0.0f, 0.0f };
        if (p < 5) {
            for (int s = 0; s < 2; ++s) {
                int o = 2 * p + s;
                float a = b1[h * 10 + o];
                for (int i = 0; i < 3; ++i)
                    a += emb[idx * 3 + i] * W1[(h * 8 + i) * 10 + o];
                for (int q = 0; q < 5; ++q)
                    a += bf[q] * W1[(h * 8 + 3 + q) * 10 + o];
                v[s] = a;
            }
        }
        wsh[WS_T + t] = hv2{ (_Float16)v[0], (_Float16)v[1] };
    }
    if (t < HH * 16) {                           // M16[h][c*5+pp], s=15 pad
        int h = t / 16, s = t % 16;
        float v[2] = { 0.0f, 0.0f };
        if (s < 15) {
            int c = s / 5, pp = s % 5;
            for (int sd = 0; sd < 2; ++sd) {
                int o = 2 * pp + sd;
                float a = 0.0f;
                for (int q = 0; q < 5; ++q)
                    a += Wf[c * 5 + q] * W1[(h * 8 + 3 + q) * 10 + o];
                v[sd] = a;
            }
        }
        wsh[WS_M + t] = hv2{ (_Float16)v[0], (_Float16)v[1] };
    }
    if (t < HH * 8) {                            // WB[h]: W2h*5, b2, Wo, pad
        int h = t / 8, s = t % 8;
        float outv = 0.0f;
        if (s < 5)
            outv = __builtin_bit_cast(float,
                       hv2{ (_Float16)W2[h * 10 + 2 * s],
                            (_Float16)W2[h * 10 + 2 * s + 1] });
        else if (s == 5) outv = b2[h];
        else if (s == 6) outv = Wo[h];
        ws[WS_WB + t] = outv;
    }
}

// -------- main: full item (20 heads) per thread --------
__global__ __launch_bounds__(NT, 6) void airfit_kernel(
    const int*   __restrict__ e,   const float* __restrict__ f,
    const float* __restrict__ ws,  const float* __restrict__ bo,
    float* __restrict__ out, int B)
{
    __shared__ __align__(16) float s_c[WS_END];  // 8,160 B

    const int tid  = threadIdx.x;
    const int base = blockIdx.x * NT;
    const int nIt  = min(NT, B - base);

    for (int t = tid; t < WS_END; t += NT) s_c[t] = ws[t];
    __syncthreads();                             // only barrier

    if (tid >= nIt) return;
    const int item = base + tid;

    // ---- e: 5x int4 (16B-aligned: item*80B) -> 20 nibbles in 3 dwords ----
    const int4* eg = reinterpret_cast<const int4*>(e + (size_t)item * HH);
    int4 e0 = eg[0], e1 = eg[1], e2 = eg[2], e3 = eg[3], e4 = eg[4];
    unsigned ew0 = (unsigned)(e0.x & 15)        | ((unsigned)(e0.y & 15) << 4)
                 | ((unsigned)(e0.z & 15) << 8) | ((unsigned)(e0.w & 15) << 12)
                 | ((unsigned)(e1.x & 15) << 16)| ((unsigned)(e1.y & 15) << 20)
                 | ((unsigned)(e1.z & 15) << 24)| ((unsigned)(e1.w & 15) << 28);
    unsigned ew1 = (unsigned)(e2.x & 15)        | ((unsigned)(e2.y & 15) << 4)
                 | ((unsigned)(e2.z & 15) << 8) | ((unsigned)(e2.w & 15) << 12)
                 | ((unsigned)(e3.x & 15) << 16)| ((unsigned)(e3.y & 15) << 20)
                 | ((unsigned)(e3.z & 15) << 24)| ((unsigned)(e3.w & 15) << 28);
    unsigned ew2 = (unsigned)(e4.x & 15)        | ((unsigned)(e4.y & 15) << 4)
                 | ((unsigned)(e4.z & 15) << 8) | ((unsigned)(e4.w & 15) << 12);

    // ---- f: 15x float4 (16B-aligned: item*240B), cvt_pkrtz immediately ----
    const float4* fg = reinterpret_cast<const float4*>(f + (size_t)item * 60);
    hv2 fh[30];
#pragma unroll
    for (int k = 0; k < 15; ++k) {
        float4 v = fg[k];
        fh[2 * k]     = cvt_pk(v.x, v.y);
        fh[2 * k + 1] = cvt_pk(v.z, v.w);
    }

    const hv2* Tt = reinterpret_cast<const hv2*>(s_c + WS_T);
    const hv2* Mt = reinterpret_cast<const hv2*>(s_c + WS_M);
    const hv2 lk2 = hv2{ (_Float16)0.01f, (_Float16)0.01f };

    float acc = bo[0];
#pragma unroll
    for (int h = 0; h < HH; ++h) {               // h compile-time
        unsigned word = (h < 8) ? ew0 : ((h < 16) ? ew1 : ew2);
        int idx = (int)((word >> (4 * (h & 7))) & 0xfu);

        const hv2* Tr = Tt + (h * NEX + idx) * 6;
        hv2 tp[5] = { Tr[0], Tr[1], Tr[2], Tr[3], Tr[4] };

        // f floats 3h..3h+2 out of fh[30] (pair index (3h)>>1, max 29)
        const int kb = (3 * h) >> 1;
        _Float16 x0, x1, x2;
        if ((h & 1) == 0) { x0 = fh[kb].x;  x1 = fh[kb].y;   x2 = fh[kb+1].x; }
        else              { x0 = fh[kb].y;  x1 = fh[kb+1].x; x2 = fh[kb+1].y; }
        hv2 g0 = hv2{ x0, x0 }, g1 = hv2{ x1, x1 }, g2 = hv2{ x2, x2 };

        const hv2*   Mh  = Mt + h * 16;          // uniform addr -> broadcast
        const float* wb  = s_c + WS_WB + h * 8;
        const hv2*   W2h = reinterpret_cast<const hv2*>(wb);

        float hacc = wb[5];                      // b2[h]
#pragma unroll
        for (int p = 0; p < 5; ++p) {
            hv2 v = g0 * Mh[p] + tp[p];          // v_pk_fma_f16
            v = g1 * Mh[5 + p] + v;
            v = g2 * Mh[10 + p] + v;
            v = __builtin_elementwise_max(v, v * lk2);  // leaky
            hacc = fdot2f(v, W2h[p], hacc);      // f32 accumulate
        }
        acc = fmaf(softplus_fast(hacc), wb[6], acc);    // Wo[h]
    }

    out[item] = acc;                             // coalesced, no atomics
}

extern "C" void kernel_launch(void* const* d_in, const int* in_sizes, int n_in,
                              void* d_out, int out_size, void* d_ws, size_t ws_size,
                              hipStream_t stream) {
    const int*   e   = (const int*)  d_in[0];
    const float* f   = (const float*)d_in[1];
    const float* emb = (const float*)d_in[2];
    const float* Wf  = (const float*)d_in[3];
    const float* bf  = (const float*)d_in[4];
    const float* W1  = (const float*)d_in[5];
    const float* b1  = (const float*)d_in[6];
    const float* W2  = (const float*)d_in[7];
    const float* b2  = (const float*)d_in[8];
    const float* Wo  = (const float*)d_in[9];
    const float* bo  = (const float*)d_in[10];
    float* out = (float*)d_out;
    float* ws  = (float*)d_ws;

    int B = in_sizes[0] / HH;                    // e is (B, 20)

    int sblocks = (HH * NEX * 6 + 255) / 256;    // 7 blocks covers all tables
    airfit_setup<<<sblocks, 256, 0, stream>>>(emb, Wf, bf, W1, b1, W2, b2, Wo, ws);

    int blocks = (B + NT - 1) / NT;
    airfit_kernel<<<blocks, NT, 0, stream>>>(e, f, ws, bo, out, B);
}